// Round 1
// baseline (253.371 us; speedup 1.0000x reference)
//
#include <hip/hip_runtime.h>

// EMA recurrence over s for x[4, 4096, 2048] fp32.
// Exact two-pass chunked scan:
//   K1: per-(col4, chunk) local EMA (zero init) -> chunk finals f_j in ws
//   K2: carry E_{j-1} = Horner over f_0..f_{j-1} with alpha^L, then rescan chunk
//       from x with correct carry, write out.

namespace {

constexpr int B  = 4;
constexpr int S  = 4096;
constexpr int D  = 2048;
constexpr int D4 = D / 4;          // 512 float4 per (b,s) row
constexpr int NCHUNK = 32;
constexpr int L  = S / NCHUNK;     // 128 = 2^7 (squaring trick in k2 depends on this)
constexpr int NCOL4 = B * D4;      // 2048 float4-columns
constexpr int BLOCK = 256;

// Match the reference's fp32 constants exactly:
// alpha = float32(0.99); one_m = float32(1.0 - 0.99)  (NOT 1.0f - 0.99f)
constexpr float kA  = 0.99f;                    // nearest float to 0.99
constexpr float kOm = (float)(1.0 - 0.99);      // 0.009999999776482582f

__global__ __launch_bounds__(BLOCK)
void cema_k1_finals(const float4* __restrict__ x, float4* __restrict__ ws) {
    const int c  = blockIdx.x * BLOCK + threadIdx.x;   // col4 index, 0..2047
    const int j  = blockIdx.y;                         // chunk index, 0..31
    const int b  = c >> 9;                             // c / D4
    const int d4 = c & (D4 - 1);

    const size_t base = ((size_t)b * S + (size_t)j * L) * D4 + d4;
    const float4* p = x + base;

    float e0 = 0.f, e1 = 0.f, e2 = 0.f, e3 = 0.f;
#pragma unroll 8
    for (int t = 0; t < L; ++t) {
        float4 v = p[(size_t)t * D4];
        e0 = kA * e0 + kOm * v.x;
        e1 = kA * e1 + kOm * v.y;
        e2 = kA * e2 + kOm * v.z;
        e3 = kA * e3 + kOm * v.w;
    }
    ws[(size_t)c * NCHUNK + j] = make_float4(e0, e1, e2, e3);
}

__global__ __launch_bounds__(BLOCK)
void cema_k2_apply(const float4* __restrict__ x, const float4* __restrict__ ws,
                   float4* __restrict__ out) {
    const int c  = blockIdx.x * BLOCK + threadIdx.x;
    const int j  = blockIdx.y;
    const int b  = c >> 9;
    const int d4 = c & (D4 - 1);

    // alpha^L exactly, via double squaring (L = 128 = 2^7)
    float aL;
    {
        double t = 0.99;
        for (int i = 0; i < 7; ++i) t *= t;
        aL = (float)t;
    }

    // Carry into chunk j: E_{j-1} = sum_{i<j} f_i * aL^(j-1-i), Horner ascending.
    float E0 = 0.f, E1 = 0.f, E2 = 0.f, E3 = 0.f;
    const float4* wsc = ws + (size_t)c * NCHUNK;
    for (int i = 0; i < j; ++i) {     // j is block-uniform: no divergence
        float4 f = wsc[i];
        E0 = E0 * aL + f.x;
        E1 = E1 * aL + f.y;
        E2 = E2 * aL + f.z;
        E3 = E3 * aL + f.w;
    }

    const size_t base = ((size_t)b * S + (size_t)j * L) * D4 + d4;
    const float4* p = x + base;
    float4* q = out + base;

#pragma unroll 8
    for (int t = 0; t < L; ++t) {
        float4 v = p[(size_t)t * D4];
        E0 = kA * E0 + kOm * v.x;
        E1 = kA * E1 + kOm * v.y;
        E2 = kA * E2 + kOm * v.z;
        E3 = kA * E3 + kOm * v.w;
        q[(size_t)t * D4] = make_float4(E0, E1, E2, E3);
    }
}

} // namespace

extern "C" void kernel_launch(void* const* d_in, const int* in_sizes, int n_in,
                              void* d_out, int out_size, void* d_ws, size_t ws_size,
                              hipStream_t stream) {
    const float4* x  = (const float4*)d_in[0];
    float4* out      = (float4*)d_out;
    float4* ws       = (float4*)d_ws;   // needs NCOL4*NCHUNK*16 B = 1 MiB

    dim3 grid(NCOL4 / BLOCK, NCHUNK);
    cema_k1_finals<<<grid, BLOCK, 0, stream>>>(x, ws);
    cema_k2_apply <<<grid, BLOCK, 0, stream>>>(x, ws, out);
}

// Round 3
// 253.156 us; speedup vs baseline: 1.0009x; 1.0009x over previous
//
#include <hip/hip_runtime.h>

// EMA recurrence over s for x[4, 4096, 2048] fp32.
// Exact two-pass chunked scan:
//   K1: per-(col4, chunk) local EMA (zero init) -> chunk finals f_j in ws
//       (layout ws[j*NCOL4 + c], coalesced both ways)
//   K2: carry E_{j-1} = Horner over f_0..f_{j-1} with alpha^L, then rescan
//       chunk from x with correct carry, write out (nontemporal stores so
//       x stays L3-resident for the re-read).

namespace {

constexpr int B  = 4;
constexpr int S  = 4096;
constexpr int D  = 2048;
constexpr int D4 = D / 4;          // 512 float4 per (b,s) row
constexpr int NCOL4 = B * D4;      // 2048 float4-columns
constexpr int BLOCK = 256;

// Native vector type for nontemporal builtins (HIP_vector_type is rejected).
typedef float v4f __attribute__((ext_vector_type(4)));

// Match the reference's fp32 constants exactly:
// alpha = float32(0.99); one_m = float32(1.0 - 0.99)  (NOT 1.0f - 0.99f)
constexpr float kA  = 0.99f;
constexpr float kOm = (float)(1.0 - 0.99);      // 0.009999999776482582f

// 0.99^L in double, L a power of two (repeated squaring), then round to float.
constexpr double alpha_pow_pow2(int l) {
    double t = 0.99;
    while (l > 1) { t *= t; l >>= 1; }
    return t;
}

template <int NCHUNK>
__global__ __launch_bounds__(BLOCK)
void cema_k1_finals(const float4* __restrict__ x, float4* __restrict__ ws) {
    constexpr int L = S / NCHUNK;
    const int c  = blockIdx.x * BLOCK + threadIdx.x;   // col4 index, 0..NCOL4-1
    const int j  = blockIdx.y;                         // chunk index
    const int b  = c >> 9;                             // c / D4
    const int d4 = c & (D4 - 1);

    const size_t base = ((size_t)b * S + (size_t)j * L) * D4 + d4;
    const float4* p = x + base;

    float e0 = 0.f, e1 = 0.f, e2 = 0.f, e3 = 0.f;
#pragma unroll 8
    for (int t = 0; t < L; ++t) {
        float4 v = p[(size_t)t * D4];
        e0 = kA * e0 + kOm * v.x;
        e1 = kA * e1 + kOm * v.y;
        e2 = kA * e2 + kOm * v.z;
        e3 = kA * e3 + kOm * v.w;
    }
    ws[(size_t)j * NCOL4 + c] = make_float4(e0, e1, e2, e3);
}

template <int NCHUNK>
__global__ __launch_bounds__(BLOCK)
void cema_k2_apply(const float4* __restrict__ x, const float4* __restrict__ ws,
                   float4* __restrict__ out) {
    constexpr int L = S / NCHUNK;
    constexpr float aL = (float)alpha_pow_pow2(L);

    const int c  = blockIdx.x * BLOCK + threadIdx.x;
    const int j  = blockIdx.y;
    const int b  = c >> 9;
    const int d4 = c & (D4 - 1);

    // Carry into chunk j: E_{j-1} = sum_{i<j} f_i * aL^(j-1-i), Horner ascending.
    // ws reads are coalesced (lanes consecutive in c).
    float E0 = 0.f, E1 = 0.f, E2 = 0.f, E3 = 0.f;
#pragma unroll 4
    for (int i = 0; i < j; ++i) {     // j is block-uniform: no divergence
        float4 f = ws[(size_t)i * NCOL4 + c];
        E0 = E0 * aL + f.x;
        E1 = E1 * aL + f.y;
        E2 = E2 * aL + f.z;
        E3 = E3 * aL + f.w;
    }

    const size_t base = ((size_t)b * S + (size_t)j * L) * D4 + d4;
    const float4* p = x + base;
    v4f* q = (v4f*)(out + base);

#pragma unroll 8
    for (int t = 0; t < L; ++t) {
        float4 v = p[(size_t)t * D4];
        E0 = kA * E0 + kOm * v.x;
        E1 = kA * E1 + kOm * v.y;
        E2 = kA * E2 + kOm * v.z;
        E3 = kA * E3 + kOm * v.w;
        v4f o = {E0, E1, E2, E3};
        __builtin_nontemporal_store(o, &q[(size_t)t * D4]);
    }
}

template <int NCHUNK>
void launch(const float4* x, float4* ws, float4* out, hipStream_t stream) {
    dim3 grid(NCOL4 / BLOCK, NCHUNK);
    cema_k1_finals<NCHUNK><<<grid, BLOCK, 0, stream>>>(x, ws);
    cema_k2_apply<NCHUNK><<<grid, BLOCK, 0, stream>>>(x, ws, out);
}

} // namespace

extern "C" void kernel_launch(void* const* d_in, const int* in_sizes, int n_in,
                              void* d_out, int out_size, void* d_ws, size_t ws_size,
                              hipStream_t stream) {
    const float4* x  = (const float4*)d_in[0];
    float4* out      = (float4*)d_out;
    float4* ws       = (float4*)d_ws;

    // Pick the largest chunk count whose finals table fits d_ws.
    const size_t per_chunk = (size_t)NCOL4 * sizeof(float4);
    if (ws_size >= 128 * per_chunk)      launch<128>(x, ws, out, stream);
    else if (ws_size >= 64 * per_chunk)  launch<64>(x, ws, out, stream);
    else                                 launch<32>(x, ws, out, stream);
}